// Round 5
// baseline (1908.153 us; speedup 1.0000x reference)
//
#include <hip/hip_runtime.h>

// SimpleRNN (relu) scan: B=512, T=512, D=64, H=512, O=1.
// R7 design: fully wave-decoupled scan. No barriers, no LDS in the main loop.
//  - 32 groups x 16 rows; 2 blocks/group (s=0: cols 0..255, s=1: 256..511);
//    8 waves/block, wave w owns 32 cols (2 n-frags), full K=576 in 144 regs/lane.
//  - Per-wave publish: wave w's h chunk is the contiguous 1KB region w of its
//    slice (A-frag order). 8x 2B stores -> vmcnt(0) -> per-wave MONOTONIC flag
//    (flags[g][ss][w] = t+1; never reset => livelock-free). Proven primitives
//    only: relaxed agent atomics for flags, sc0 loads for data (R5-validated
//    same-L2 visibility; XCD handshake falls back to fenced protocol).
//  - Per-wave acquire: poll 16 flags (one per lane), then 16x global_load_dwordx4
//    sc0 DIRECTLY into A-frag registers; manual s_waitcnt vmcnt(15-j) +
//    sched_barrier(0) before each use (inline-asm loads are invisible to the
//    compiler's waitcnt insertion).
//  - Ring-2 slot reuse safety: producer at step t overwrites slot t&1 only after
//    observing all flags >= t, which transitively orders after every reader's
//    step-(t-1) loads (loads retire before that reader's own flag store).
//  - x A-frags built per-wave from global f32 (L1/L2-resident stream), 1-step
//    pipelined; no shared staging.
//  - Waves skew <=1 step via data deps; skew lets MFMA pipe overlap transport.
//  - LDS used only by the output head (s==0, after the loop).

#define T_STEPS 512
#define D_IN    64
#define ROWS    16
#define THREADS 512

#define WT_OFF    0
#define WT_BYTES  (512*576*2)            // 589824
#define HBUF_OFF  WT_BYTES
#define HBUF_BYTES (32*2*2*8192)         // 1 MiB: (g, ss, slot) slices of 8KB
#define FLAGS_OFF (HBUF_OFF + HBUF_BYTES)
#define FLAGS_BYTES (32*16*4)            // 2 KiB: monotonic per (g, ss, w)
#define XTAB_BYTES 256                   // 64 ints: per-block XCD id (+1)

typedef float  floatx4 __attribute__((ext_vector_type(4)));
typedef __bf16 bf16x8  __attribute__((ext_vector_type(8)));
typedef unsigned int uintx4 __attribute__((ext_vector_type(4)));

__device__ __forceinline__ unsigned short f2b(float f) {
    union { float f; unsigned int u; } v; v.f = f;
    unsigned int u = v.u;
    return (unsigned short)((u + 0x7FFFu + ((u >> 16) & 1u)) >> 16);  // RNE
}

__device__ __forceinline__ bf16x8 make_bf8(floatx4 a, floatx4 b) {
    union { unsigned int u[4]; bf16x8 v; } r;
    r.u[0] = (unsigned)f2b(a[0]) | ((unsigned)f2b(a[1]) << 16);
    r.u[1] = (unsigned)f2b(a[2]) | ((unsigned)f2b(a[3]) << 16);
    r.u[2] = (unsigned)f2b(b[0]) | ((unsigned)f2b(b[1]) << 16);
    r.u[3] = (unsigned)f2b(b[2]) | ((unsigned)f2b(b[3]) << 16);
    return r.v;
}

// WT element f = ((ng*18 + kc)*64 + lane)*8 + j  encodes B[k][n]:
//   n = ng*16 + (lane&15),  k = kc*32 + (lane>>4)*8 + j
__global__ void prep_kernel(const float* __restrict__ Wx, const float* __restrict__ Wh,
                            unsigned short* __restrict__ WT) {
    int f = blockIdx.x * 256 + threadIdx.x;
    if (f >= 512 * 576) return;
    int j    = f & 7;
    int lane = (f >> 3) & 63;
    int blk  = f >> 9;
    int kc   = blk % 18;
    int ng   = blk / 18;
    int n = ng * 16 + (lane & 15);
    int k = kc * 32 + (lane >> 4) * 8 + j;
    float val = (k < 64) ? Wx[k * 512 + n] : Wh[(k - 64) * 512 + n];
    WT[f] = f2b(val);
}

__global__ __launch_bounds__(THREADS, 2)
void rnn_scan_kernel(const float* __restrict__ x, const unsigned short* __restrict__ WT,
                     const float* __restrict__ b_rnn, const float* __restrict__ Wd,
                     const float* __restrict__ bd, float* __restrict__ out,
                     unsigned short* __restrict__ hbuf, int* __restrict__ flags) {
    __shared__ __attribute__((aligned(16))) unsigned short hlds[18 * 512]; // head only
    __shared__ int s_same;

    const int tid  = threadIdx.x;
    const int lane = tid & 63;
    const int w    = tid >> 6;
    const int c    = lane & 15;
    const int quad = lane >> 4;
    const int g     = blockIdx.x & 31;
    const int s     = blockIdx.x >> 5;
    const int r0    = g * ROWS;

    int* xtab = flags + 32 * 16;
    int spin_budget = 1 << 24;   // cumulative; exhaustion -> proceed, never hang

    // ---- publish own XCD id early ----
    int myx = -1;
    if (tid == 0) {
        unsigned xr;
        asm volatile("s_getreg_b32 %0, hwreg(HW_REG_XCC_ID)" : "=s"(xr));
        myx = (int)xr;
        __hip_atomic_store(&xtab[blockIdx.x], myx + 1,
                           __ATOMIC_RELAXED, __HIP_MEMORY_SCOPE_AGENT);
    }

    // ---- weights -> registers, natural kc order (A-slot i <-> WT kc=i) ----
    bf16x8 wreg[18][2];
#pragma unroll
    for (int i = 0; i < 18; ++i) {
#pragma unroll
        for (int nt = 0; nt < 2; ++nt) {
            const int ng = s * 16 + w * 2 + nt;
            wreg[i][nt] = *reinterpret_cast<const bf16x8*>(
                WT + (((size_t)ng * 18 + i) * 64 + lane) * 8);
        }
    }

    float bias[2];
#pragma unroll
    for (int nt = 0; nt < 2; ++nt)
        bias[nt] = b_rnn[s * 256 + w * 32 + nt * 16 + c];

    // ---- resolve placement: same XCD as pair peer? ----
    if (tid == 0) {
        const int pb = (1 - s) * 32 + g;
        int pv;
        while ((pv = __hip_atomic_load(&xtab[pb], __ATOMIC_RELAXED,
                                       __HIP_MEMORY_SCOPE_AGENT)) == 0
               && --spin_budget > 0) {}
        s_same = (pv != 0 && pv == myx + 1) ? 1 : 0;
    }
    __syncthreads();
    const bool sameXcd = (s_same != 0);

    // producer scatter offsets (shorts) within own slice; chunk w region is
    // [w*512, (w+1)*512) since cl>>5 == w for cl in [32w, 32w+32)
    int soff[2];
#pragma unroll
    for (int nt = 0; nt < 2; ++nt) {
        const int cl = w * 32 + nt * 16 + c;
        soff[nt] = (((cl >> 5) * 64) + (((cl >> 3) & 3) * 16) + quad * 4) * 8 + (cl & 7);
    }

    // flags: fb[l] = flags[g*16 + ss*8 + w'], lane l polls fb[l] (l<16)
    int* fb   = flags + g * 16;
    int* ownf = fb + s * 8 + w;
    int* pollp = fb + (lane < 16 ? lane : 0);

    // h transport bases
    const char* hb = (const char*)hbuf + (size_t)g * 32768 + (size_t)lane * 16;
    unsigned short* psl[2];
#pragma unroll
    for (int sl = 0; sl < 2; ++sl)
        psl[sl] = (unsigned short*)((char*)hbuf + (size_t)g * 32768 + s * 16384 + sl * 8192);

    // x: lane covers row r0+c, k = kc*32 + quad*8 + [0,8)
    const float* xrow = x + ((size_t)(r0 + c) * T_STEPS) * D_IN + quad * 8;

    floatx4 xl0, xl1, xl2, xl3;   // raw f32 for current-step frags
    {
        const float* p = xrow;                        // t = 0
        xl0 = *(const floatx4*)(p);      xl1 = *(const floatx4*)(p + 4);
        xl2 = *(const floatx4*)(p + 32); xl3 = *(const floatx4*)(p + 36);
    }

    for (int t = 0; t < T_STEPS; ++t) {
        // convert this step's x frags, then kick next step's x loads
        bf16x8 xf0 = make_bf8(xl0, xl1);
        bf16x8 xf1 = make_bf8(xl2, xl3);
        if (t + 1 < T_STEPS) {
            const float* p = xrow + (size_t)(t + 1) * D_IN;
            xl0 = *(const floatx4*)(p);      xl1 = *(const floatx4*)(p + 4);
            xl2 = *(const floatx4*)(p + 32); xl3 = *(const floatx4*)(p + 36);
        }

        uintx4 hf[16];
        if (t > 0) {
            // poll all 16 per-wave flags (monotonic): need >= t
            for (;;) {
                int fv = __hip_atomic_load(pollp, __ATOMIC_RELAXED, __HIP_MEMORY_SCOPE_AGENT);
                int ok = (lane >= 16) || (fv >= t);
                if (__all(ok)) break;
                if (--spin_budget <= 0) break;
            }
            if (!sameXcd) __builtin_amdgcn_fence(__ATOMIC_ACQUIRE, "agent");
            // issue 16 chunk loads straight into registers (sc0: read shared L2)
            const unsigned slotoff = (unsigned)(((t - 1) & 1) * 8192);
#pragma unroll
            for (int j = 0; j < 16; ++j) {
                const char* p = hb + slotoff + (unsigned)((j >> 3) * 16384 + (j & 7) * 1024);
                asm volatile("global_load_dwordx4 %0, %1, off sc0"
                             : "=v"(hf[j]) : "v"(p) : "memory");
            }
        }

        floatx4 acc0 = {0.f, 0.f, 0.f, 0.f}, acc1 = {0.f, 0.f, 0.f, 0.f};

        // x contribution (slots 0..1) while h loads fly
        acc0 = __builtin_amdgcn_mfma_f32_16x16x32_bf16(xf0, wreg[0][0], acc0, 0, 0, 0);
        acc1 = __builtin_amdgcn_mfma_f32_16x16x32_bf16(xf0, wreg[0][1], acc1, 0, 0, 0);
        acc0 = __builtin_amdgcn_mfma_f32_16x16x32_bf16(xf1, wreg[1][0], acc0, 0, 0, 0);
        acc1 = __builtin_amdgcn_mfma_f32_16x16x32_bf16(xf1, wreg[1][1], acc1, 0, 0, 0);

        if (t > 0) {
            // h contribution: manual waits (asm loads are invisible to compiler
            // waitcnt insertion); sched_barrier stops MFMA hoisting (rule #18)
#pragma unroll
            for (int j = 0; j < 16; ++j) {
                asm volatile("s_waitcnt vmcnt(%0)" :: "i"(15 - j) : "memory");
                __builtin_amdgcn_sched_barrier(0);
                union { uintx4 u; bf16x8 b; } cv; cv.u = hf[j];
                acc0 = __builtin_amdgcn_mfma_f32_16x16x32_bf16(cv.b, wreg[2 + j][0], acc0, 0, 0, 0);
                acc1 = __builtin_amdgcn_mfma_f32_16x16x32_bf16(cv.b, wreg[2 + j][1], acc1, 0, 0, 0);
            }
        }

        // epilogue: relu+pack h_t -> own chunk of slice slot t&1 (8x 2B stores)
        unsigned short* ps = psl[t & 1];
#pragma unroll
        for (int nt = 0; nt < 2; ++nt) {
#pragma unroll
            for (int r = 0; r < 4; ++r) {
                float v = (nt ? acc1[r] : acc0[r]) + bias[nt];
                v = v > 0.f ? v : 0.f;
                ps[soff[nt] + r * 8] = f2b(v);
            }
        }
        // drain own stores to L2, then publish per-wave monotonic flag
        asm volatile("s_waitcnt vmcnt(0)" ::: "memory");
        if (!sameXcd) __builtin_amdgcn_fence(__ATOMIC_RELEASE, "agent");
        if (lane == 0)
            __hip_atomic_store(ownf, t + 1, __ATOMIC_RELAXED, __HIP_MEMORY_SCOPE_AGENT);
    }

    // ---- output head: only s==0 finalizes (needs full h_511, slot 1) ----
    if (s == 0) {
        for (;;) {
            int fv = __hip_atomic_load(pollp, __ATOMIC_RELAXED, __HIP_MEMORY_SCOPE_AGENT);
            int ok = (lane >= 16) || (fv >= T_STEPS);
            if (__all(ok)) break;
            if (--spin_budget <= 0) break;
        }
        if (!sameXcd) __builtin_amdgcn_fence(__ATOMIC_ACQUIRE, "agent");
        uintx4 h0, h1;
        {
            const char* p0 = hb + 8192 + (unsigned)((w & 7) * 1024);          // ss=0 chunk w
            const char* p1 = hb + 8192 + (unsigned)(16384 + (w & 7) * 1024);  // ss=1 chunk w
            asm volatile("global_load_dwordx4 %0, %1, off sc0" : "=v"(h0) : "v"(p0) : "memory");
            asm volatile("global_load_dwordx4 %0, %1, off sc0" : "=v"(h1) : "v"(p1) : "memory");
            asm volatile("s_waitcnt vmcnt(0)" ::: "memory");
            __builtin_amdgcn_sched_barrier(0);
        }
        *reinterpret_cast<uintx4*>(&hlds[(2 + w) * 512 + lane * 8]) = h0;
        *reinterpret_cast<uintx4*>(&hlds[(10 + w) * 512 + lane * 8]) = h1;
        __syncthreads();

        const int lane5 = lane & 31;
        const int row = w * 2 + (lane >> 5);
        float sum = 0.f;
#pragma unroll
        for (int b2 = 0; b2 < 2; ++b2) {
            const int col0 = lane5 * 16 + b2 * 8;
            const int kcp = 2 + (col0 >> 5);
            const int q2 = (col0 >> 3) & 3;
            const bf16x8 hvv = *reinterpret_cast<const bf16x8*>(&hlds[kcp * 512 + (q2 * 16 + row) * 8]);
#pragma unroll
            for (int jj = 0; jj < 8; ++jj)
                sum += (float)hvv[jj] * Wd[col0 + jj];
        }
#pragma unroll
        for (int off = 1; off < 32; off <<= 1) sum += __shfl_xor(sum, off, 64);
        if (lane5 == 0) {
            float v = sum + bd[0];
            out[r0 + row] = v > 0.f ? v : 0.f;
        }
    }
}

extern "C" void kernel_launch(void* const* d_in, const int* in_sizes, int n_in,
                              void* d_out, int out_size, void* d_ws, size_t ws_size,
                              hipStream_t stream) {
    const float* x    = (const float*)d_in[0];
    const float* Wx   = (const float*)d_in[1];
    const float* Wh   = (const float*)d_in[2];
    const float* brnn = (const float*)d_in[3];
    const float* Wd   = (const float*)d_in[4];
    const float* bd   = (const float*)d_in[5];
    float* out = (float*)d_out;

    char* wsb = (char*)d_ws;
    unsigned short* WT   = (unsigned short*)(wsb + WT_OFF);
    unsigned short* hbuf = (unsigned short*)(wsb + HBUF_OFF);
    int*            flg  = (int*)(wsb + FLAGS_OFF);

    hipMemsetAsync(wsb + FLAGS_OFF, 0, FLAGS_BYTES + XTAB_BYTES, stream);
    prep_kernel<<<(512 * 576 + 255) / 256, 256, 0, stream>>>(Wx, Wh, WT);
    rnn_scan_kernel<<<64, THREADS, 0, stream>>>(x, WT, brnn, Wd, bd, out, hbuf, flg);
}

// Round 7
// 1233.763 us; speedup vs baseline: 1.5466x; 1.5466x over previous
//
#include <hip/hip_runtime.h>

// SimpleRNN (relu) scan: B=512, T=512, D=64, H=512, O=1.
// R9 design: R5's proven exchange protocol, 4-wave geometry (halved LDS traffic),
// per-wave flags (publish without block barrier).
//  - 32 groups x 16 rows; 2 blocks/group (s=0: cols 0..255, s=1: 256..511).
//  - 256 threads = 4 waves; wave w owns 64 cols (4 n-frags); weights 576x64 bf16
//    = 288 VGPRs/lane, register-resident (launch_bounds(256,1) -> 512 VGPR budget).
//  - Exchange (R5 primitives verbatim): per-wave flag (relaxed agent atomic,
//    one per (g,s,t,w)); consumer wave w polls its MIRROR wave's flag, loads peer
//    chunks {2w,2w+1} with global_load_dwordx4 sc0, lands into LDS after phase-1
//    (vmcnt(0)+sched_barrier). Publish: per-wave vmcnt(0) drain -> flag store,
//    NO barrier on publish path. Cross-XCD fallback: acquire/release fences.
//  - Ring-2 slot reuse safety: wave w writes slot t&1 only after seeing peer
//    wave w's flag(t-1), which transitively orders after peer's read of our
//    chunk (t-2) data (same argument as R5, per wave pair).
//  - x staged into afrag by all threads (floatx4 load, 4x f2b, one 8B LDS write),
//    pipelined 2 deep, loads issued after the tail drain (R5 pattern).

#define T_STEPS 512
#define D_IN    64
#define ROWS    16
#define THREADS 256

#define WT_OFF    0
#define WT_BYTES  (512*576*2)            // 589824
#define HBUF_OFF  WT_BYTES
#define HBUF_BYTES (32*2*2*8192)         // 1 MiB: (g, slot, ss) 8KB slices
#define FLAGS_OFF (HBUF_OFF + HBUF_BYTES)
#define FLAGS_BYTES (32*2*512*4*4)       // 512 KiB: per (g, s, t, w)
#define XTAB_BYTES 256                   // 64 ints: per-block XCD id (+1)

typedef float  floatx4 __attribute__((ext_vector_type(4)));
typedef __bf16 bf16x8  __attribute__((ext_vector_type(8)));
typedef unsigned int uintx4 __attribute__((ext_vector_type(4)));
typedef unsigned int uintx2 __attribute__((ext_vector_type(2)));

__device__ __forceinline__ unsigned short f2b(float f) {
    union { float f; unsigned int u; } v; v.f = f;
    unsigned int u = v.u;
    return (unsigned short)((u + 0x7FFFu + ((u >> 16) & 1u)) >> 16);  // RNE
}

// WT element f = ((ng*18 + kc)*64 + lane)*8 + j  encodes B[k][n]:
//   n = ng*16 + (lane&15),  k = kc*32 + (lane>>4)*8 + j
__global__ void prep_kernel(const float* __restrict__ Wx, const float* __restrict__ Wh,
                            unsigned short* __restrict__ WT) {
    int f = blockIdx.x * 256 + threadIdx.x;
    if (f >= 512 * 576) return;
    int j    = f & 7;
    int lane = (f >> 3) & 63;
    int blk  = f >> 9;
    int kc   = blk % 18;
    int ng   = blk / 18;
    int n = ng * 16 + (lane & 15);
    int k = kc * 32 + (lane >> 4) * 8 + j;
    float val = (k < 64) ? Wx[k * 512 + n] : Wh[(k - 64) * 512 + n];
    WT[f] = f2b(val);
}

__global__ __launch_bounds__(THREADS, 1)
void rnn_scan_kernel(const float* __restrict__ x, const unsigned short* __restrict__ WT,
                     const float* __restrict__ b_rnn, const float* __restrict__ Wd,
                     const float* __restrict__ bd, float* __restrict__ out,
                     unsigned short* __restrict__ hbuf, int* __restrict__ flags) {
    // afrag[(kc*64 + lane)*8 + j]: A[m = lane&15, k = kc*32 + (lane>>4)*8 + j]
    // kc 0..1 = x_t (k<64); kc 2..9 = h cols 0..255; kc 10..17 = h cols 256..511.
    __shared__ __attribute__((aligned(16))) unsigned short afrag[18 * 512]; // 18 KB
    __shared__ int s_same;

    const int tid  = threadIdx.x;
    const int lane = tid & 63;
    const int w    = tid >> 6;          // 0..3
    const int c    = lane & 15;
    const int quad = lane >> 4;
    const int g     = blockIdx.x & 31;
    const int s     = blockIdx.x >> 5;
    const int speer = 1 - s;
    const int r0    = g * ROWS;

    int* xtab = flags + 32 * 2 * 512 * 4;
    int spin_budget = 1 << 24;   // cumulative; exhaustion -> proceed (never hang)

    // ---- publish own XCD id early ----
    int myx = -1;
    if (tid == 0) {
        unsigned xr;
        asm volatile("s_getreg_b32 %0, hwreg(HW_REG_XCC_ID)" : "=s"(xr));
        myx = (int)xr;
        __hip_atomic_store(&xtab[blockIdx.x], myx + 1,
                           __ATOMIC_RELAXED, __HIP_MEMORY_SCOPE_AGENT);
    }

    // ---- weights -> registers (slot order: 0..1 = x, 2..9 = own, 10..17 = peer) ----
    bf16x8 wreg[18][4];
#pragma unroll
    for (int i = 0; i < 18; ++i) {
        const int kcp = (i < 2) ? i : (i < 10 ? (2 + s * 8 + (i - 2))
                                              : (2 + speer * 8 + (i - 10)));
#pragma unroll
        for (int nt = 0; nt < 4; ++nt) {
            const int ng = s * 16 + w * 4 + nt;
            wreg[i][nt] = *reinterpret_cast<const bf16x8*>(
                WT + (((size_t)ng * 18 + kcp) * 64 + lane) * 8);
        }
    }

    float bias[4];
#pragma unroll
    for (int nt = 0; nt < 4; ++nt)
        bias[nt] = b_rnn[s * 256 + w * 64 + nt * 16 + c];

    // zero h region, stage x_0 (each thread: 4 consecutive elems = one 8B write)
    for (int i = tid; i < 8192; i += THREADS) afrag[1024 + i] = 0;
    const int xe = tid * 4;
    const int xm = xe >> 6;
    const int xk = xe & 63;
    const int xidx = ((xk >> 5) * 64 + ((xk >> 3) & 3) * 16 + xm) * 8 + (xk & 7);
    const float* xbase = x + ((size_t)(r0 + xm) * T_STEPS) * D_IN + xk;
    {
        floatx4 x0 = *reinterpret_cast<const floatx4*>(xbase);
        uintx2 xw;
        xw[0] = (unsigned)f2b(x0[0]) | ((unsigned)f2b(x0[1]) << 16);
        xw[1] = (unsigned)f2b(x0[2]) | ((unsigned)f2b(x0[3]) << 16);
        *reinterpret_cast<uintx2*>(&afrag[xidx]) = xw;
    }

    // ---- resolve placement ----
    if (tid == 0) {
        const int pb = speer * 32 + g;
        int pv;
        while ((pv = __hip_atomic_load(&xtab[pb], __ATOMIC_RELAXED,
                                       __HIP_MEMORY_SCOPE_AGENT)) == 0
               && --spin_budget > 0) {}
        s_same = (pv != 0 && pv == myx + 1) ? 1 : 0;
    }
    __syncthreads();
    const bool sameXcd = (s_same != 0);

    const char* ab = (const char*)afrag;
    const unsigned laneoff = (unsigned)lane * 16u;
    const unsigned ownB  = laneoff + (unsigned)s * 8192u;      // + i*1024, i in [2,10)
    const unsigned peerB = laneoff + (unsigned)speer * 8192u;  // + (i-8)*1024, i in [10,18)
    const int peerLdsByte = (2 + speer * 8) * 1024;
    const int ownLds = (2 + s * 8) * 512;   // short index base

    // epilogue short-offsets within slice (r=0); m = quad*4+r -> +8 per r
    int soff[4];
#pragma unroll
    for (int nt = 0; nt < 4; ++nt) {
        const int cl = w * 64 + nt * 16 + c;
        soff[nt] = (((cl >> 5) * 64) + (((cl >> 3) & 3) * 16) + quad * 4) * 8 + (cl & 7);
    }

    // ---- x pipeline, 2 deep ----
    floatx4 xc4 = {0,0,0,0}, xn4 = {0,0,0,0};
    xc4 = *reinterpret_cast<const floatx4*>(xbase + 1 * D_IN);
    xn4 = *reinterpret_cast<const floatx4*>(xbase + 2 * D_IN);

    for (int t = 0; t < T_STEPS; ++t) {
        // ---- exchange: poll mirror wave's flag, issue 2 chunk loads ----
        uintx4 pd0, pd1;
        const bool doex = (t > 0);
        if (doex) {
            const int* fp = flags + ((((g * 2 + speer) * 512) + (t - 1)) << 2) + w;
            const char* p0 = (const char*)hbuf
                + (((size_t)g * 4 + ((t - 1) & 1) * 2 + speer) * 8192)
                + (unsigned)(w * 2048) + laneoff;
            if (lane == 0) {
                while (__hip_atomic_load(fp, __ATOMIC_RELAXED, __HIP_MEMORY_SCOPE_AGENT) == 0
                       && --spin_budget > 0) {}
            }
            if (!sameXcd) __builtin_amdgcn_fence(__ATOMIC_ACQUIRE, "agent");
            asm volatile("global_load_dwordx4 %0, %1, off sc0"
                         : "=v"(pd0) : "v"(p0) : "memory");
            asm volatile("global_load_dwordx4 %0, %1, off sc0"
                         : "=v"(pd1) : "v"(p0 + 1024) : "memory");
        }

        floatx4 acc[4];
#pragma unroll
        for (int nt = 0; nt < 4; ++nt) acc[nt] = (floatx4){0.f, 0.f, 0.f, 0.f};

        // phase 1: x + own columns (exchange loads in flight underneath)
#pragma unroll
        for (int i = 0; i < 2; ++i) {
            bf16x8 a = *reinterpret_cast<const bf16x8*>(ab + laneoff + i * 1024);
#pragma unroll
            for (int nt = 0; nt < 4; ++nt)
                acc[nt] = __builtin_amdgcn_mfma_f32_16x16x32_bf16(a, wreg[i][nt], acc[nt], 0, 0, 0);
        }
#pragma unroll
        for (int i = 2; i < 10; ++i) {
            bf16x8 a = *reinterpret_cast<const bf16x8*>(ab + ownB + i * 1024);
#pragma unroll
            for (int nt = 0; nt < 4; ++nt)
                acc[nt] = __builtin_amdgcn_mfma_f32_16x16x32_bf16(a, wreg[i][nt], acc[nt], 0, 0, 0);
        }

        // land the exchange: wait loads, write both chunks into peer LDS region
        if (doex) {
            asm volatile("s_waitcnt vmcnt(0)" ::: "memory");
            __builtin_amdgcn_sched_barrier(0);
            *reinterpret_cast<uintx4*>((char*)afrag + peerLdsByte + w * 2048 + laneoff) = pd0;
            *reinterpret_cast<uintx4*>((char*)afrag + peerLdsByte + w * 2048 + 1024 + laneoff) = pd1;
        }
        __syncthreads();

        // phase 2: peer columns
#pragma unroll
        for (int i = 10; i < 18; ++i) {
            bf16x8 a = *reinterpret_cast<const bf16x8*>(ab + peerB + (i - 8) * 1024);
#pragma unroll
            for (int nt = 0; nt < 4; ++nt)
                acc[nt] = __builtin_amdgcn_mfma_f32_16x16x32_bf16(a, wreg[i][nt], acc[nt], 0, 0, 0);
        }

        // epilogue: relu+pack h_t -> own LDS region + global slice (A-frag order)
        unsigned short* hs = hbuf + ((size_t)g * 4 + (t & 1) * 2 + s) * 4096;
#pragma unroll
        for (int nt = 0; nt < 4; ++nt) {
#pragma unroll
            for (int r = 0; r < 4; ++r) {
                float v = acc[nt][r] + bias[nt];
                v = v > 0.f ? v : 0.f;
                const unsigned short hb = f2b(v);
                const int so = soff[nt] + r * 8;
                afrag[ownLds + so] = hb;
                hs[so] = hb;
            }
        }
        if (t < T_STEPS - 1) {
            uintx2 xw;
            xw[0] = (unsigned)f2b(xc4[0]) | ((unsigned)f2b(xc4[1]) << 16);
            xw[1] = (unsigned)f2b(xc4[2]) | ((unsigned)f2b(xc4[3]) << 16);
            *reinterpret_cast<uintx2*>(&afrag[xidx]) = xw;
        }

        // per-wave drain + flag publish (no barrier on publish path)
        asm volatile("s_waitcnt vmcnt(0)" ::: "memory");
        if (!sameXcd) __builtin_amdgcn_fence(__ATOMIC_RELEASE, "agent");
        if (lane == 0)
            __hip_atomic_store(flags + ((((g * 2 + s) * 512) + t) << 2) + w, 1,
                               __ATOMIC_RELAXED, __HIP_MEMORY_SCOPE_AGENT);
        __syncthreads();   // own-LDS h visible to all waves for next phase 1

        // rotate x pipeline; issue x(t+3) after the drain (R5 pattern)
        xc4 = xn4;
        if (t + 3 < T_STEPS)
            xn4 = *reinterpret_cast<const floatx4*>(xbase + (size_t)(t + 3) * D_IN);
    }

    // ---- output head: only s==0 finalizes (needs peer h_511, slot 1) ----
    if (s == 0) {
        const int* fp = flags + ((((g * 2 + 1) * 512) + 511) << 2) + w;
        const char* p0 = (const char*)hbuf + (((size_t)g * 4 + 1 * 2 + 1) * 8192)
                         + (unsigned)(w * 2048) + laneoff;
        if (lane == 0) {
            while (__hip_atomic_load(fp, __ATOMIC_RELAXED, __HIP_MEMORY_SCOPE_AGENT) == 0
                   && --spin_budget > 0) {}
        }
        if (!sameXcd) __builtin_amdgcn_fence(__ATOMIC_ACQUIRE, "agent");
        uintx4 pd0, pd1;
        asm volatile("global_load_dwordx4 %0, %1, off sc0" : "=v"(pd0) : "v"(p0) : "memory");
        asm volatile("global_load_dwordx4 %0, %1, off sc0" : "=v"(pd1) : "v"(p0 + 1024) : "memory");
        asm volatile("s_waitcnt vmcnt(0)" ::: "memory");
        __builtin_amdgcn_sched_barrier(0);
        *reinterpret_cast<uintx4*>((char*)afrag + peerLdsByte + w * 2048 + laneoff) = pd0;
        *reinterpret_cast<uintx4*>((char*)afrag + peerLdsByte + w * 2048 + 1024 + laneoff) = pd1;
        __syncthreads();

        // row = w*4 + quad; lane c covers cols c*32 .. c*32+31
        const int row = w * 4 + quad;
        float sum = 0.f;
#pragma unroll
        for (int k8 = 0; k8 < 4; ++k8) {
            const int col0 = c * 32 + k8 * 8;
            const bf16x8 hvv = *reinterpret_cast<const bf16x8*>(
                &afrag[(2 + c) * 512 + (k8 * 16 + row) * 8]);
#pragma unroll
            for (int jj = 0; jj < 8; ++jj)
                sum += (float)hvv[jj] * Wd[col0 + jj];
        }
#pragma unroll
        for (int off = 1; off < 16; off <<= 1) sum += __shfl_xor(sum, off, 64);
        if (c == 0) {
            float v = sum + bd[0];
            out[r0 + row] = v > 0.f ? v : 0.f;
        }
    }
}

extern "C" void kernel_launch(void* const* d_in, const int* in_sizes, int n_in,
                              void* d_out, int out_size, void* d_ws, size_t ws_size,
                              hipStream_t stream) {
    const float* x    = (const float*)d_in[0];
    const float* Wx   = (const float*)d_in[1];
    const float* Wh   = (const float*)d_in[2];
    const float* brnn = (const float*)d_in[3];
    const float* Wd   = (const float*)d_in[4];
    const float* bd   = (const float*)d_in[5];
    float* out = (float*)d_out;

    char* wsb = (char*)d_ws;
    unsigned short* WT   = (unsigned short*)(wsb + WT_OFF);
    unsigned short* hbuf = (unsigned short*)(wsb + HBUF_OFF);
    int*            flg  = (int*)(wsb + FLAGS_OFF);

    hipMemsetAsync(wsb + FLAGS_OFF, 0, FLAGS_BYTES + XTAB_BYTES, stream);
    prep_kernel<<<(512 * 576 + 255) / 256, 256, 0, stream>>>(Wx, Wh, WT);
    rnn_scan_kernel<<<64, THREADS, 0, stream>>>(x, WT, brnn, Wd, bd, out, hbuf, flg);
}